// Round 1
// baseline (126.865 us; speedup 1.0000x reference)
//
#include <hip/hip_runtime.h>
#include <math.h>

#define BLK 256
#define JSPLIT 16
#define LAM 0.1f

// ---------------- reduction helpers ----------------
__device__ __forceinline__ float wave_reduce(float v) {
    v += __shfl_down(v, 32, 64);
    v += __shfl_down(v, 16, 64);
    v += __shfl_down(v, 8, 64);
    v += __shfl_down(v, 4, 64);
    v += __shfl_down(v, 2, 64);
    v += __shfl_down(v, 1, 64);
    return v;
}

// ---------------- kernel 1: softmax probs + focal + sum(w) ----------------
// probs[N*4], scal[9]=focal_sum, scal[10]=W
__global__ __launch_bounds__(BLK) void k1_rowprep(
        const float* __restrict__ outs, const int* __restrict__ labels,
        const float* __restrict__ wts, float* __restrict__ probs,
        float* __restrict__ scal) {
    __shared__ float lds[8];
    int i = blockIdx.x * BLK + threadIdx.x;
    float4 o = ((const float4*)outs)[i];
    float m = fmaxf(fmaxf(o.x, o.y), fmaxf(o.z, o.w));
    float e0 = expf(o.x - m), e1 = expf(o.y - m), e2 = expf(o.z - m), e3 = expf(o.w - m);
    float s = e0 + e1 + e2 + e3;
    float inv = 1.0f / s;
    float4 p = make_float4(e0 * inv, e1 * inv, e2 * inv, e3 * inv);
    ((float4*)probs)[i] = p;
    int l = labels[i];
    float ol = (l == 0) ? o.x : (l == 1) ? o.y : (l == 2) ? o.z : o.w;
    float logpt = ol - m - logf(s);
    float pt = expf(logpt);
    float w = wts[i];
    float om = 1.0f - pt;
    float focal = -om * om * logpt * w;

    int lane = threadIdx.x & 63, wave = threadIdx.x >> 6;
    float fr = wave_reduce(focal);
    if (lane == 0) lds[wave] = fr;
    __syncthreads();
    if (threadIdx.x == 0) atomicAdd(&scal[9], lds[0] + lds[1] + lds[2] + lds[3]);
    __syncthreads();
    float wr = wave_reduce(w);
    if (lane == 0) lds[wave] = wr;
    __syncthreads();
    if (threadIdx.x == 0) atomicAdd(&scal[10], lds[0] + lds[1] + lds[2] + lds[3]);
}

// ---------------- kernel 2: O(N^2) pair pass ----------------
// rows[5*N] raw weighted row sums  s_v(i) = sum_j w_j |x_v_i - x_v_j|
// scal[0..3]=T_ce raw, scal[4]=T_ee raw, scal[5..8]=T_cc raw
//   (T raw = sum_ij w_i w_j d^v_ij d^w_ij)
__global__ __launch_bounds__(BLK) void k2_pairs(
        const float* __restrict__ probs, const float* __restrict__ event,
        const float* __restrict__ wts, float* __restrict__ rows,
        float* __restrict__ scal, int N) {
    __shared__ float4 jp[BLK];
    __shared__ float2 jew[BLK];
    __shared__ float red[4][9];

    int tid = threadIdx.x;
    int i = blockIdx.x * BLK + tid;
    float4 pi = ((const float4*)probs)[i];
    float ei = event[i];
    float wi = wts[i];

    int jcount = N / JSPLIT;
    int jbase = blockIdx.y * jcount;

    float s0 = 0.f, s1 = 0.f, s2 = 0.f, s3 = 0.f, se = 0.f;
    float t0e = 0.f, t1e = 0.f, t2e = 0.f, t3e = 0.f, tee = 0.f;
    float t00 = 0.f, t11 = 0.f, t22 = 0.f, t33 = 0.f;

    for (int jc = 0; jc < jcount; jc += BLK) {
        int j = jbase + jc + tid;
        jp[tid] = ((const float4*)probs)[j];
        jew[tid] = make_float2(event[j], wts[j]);
        __syncthreads();
#pragma unroll 4
        for (int jj = 0; jj < BLK; ++jj) {
            float4 p = jp[jj];
            float2 ew = jew[jj];
            float d0 = fabsf(pi.x - p.x);
            float d1 = fabsf(pi.y - p.y);
            float d2 = fabsf(pi.z - p.z);
            float d3 = fabsf(pi.w - p.w);
            float de = fabsf(ei - ew.x);
            float wj = ew.y;
            s0 = fmaf(wj, d0, s0);
            s1 = fmaf(wj, d1, s1);
            s2 = fmaf(wj, d2, s2);
            s3 = fmaf(wj, d3, s3);
            se = fmaf(wj, de, se);
            float wde = wj * de;
            t0e = fmaf(wde, d0, t0e);
            t1e = fmaf(wde, d1, t1e);
            t2e = fmaf(wde, d2, t2e);
            t3e = fmaf(wde, d3, t3e);
            tee = fmaf(wde, de, tee);
            float wd0 = wj * d0, wd1 = wj * d1, wd2 = wj * d2, wd3 = wj * d3;
            t00 = fmaf(wd0, d0, t00);
            t11 = fmaf(wd1, d1, t11);
            t22 = fmaf(wd2, d2, t22);
            t33 = fmaf(wd3, d3, t33);
        }
        __syncthreads();
    }

    // raw row sums (accumulated across j-splits)
    atomicAdd(&rows[0 * N + i], s0);
    atomicAdd(&rows[1 * N + i], s1);
    atomicAdd(&rows[2 * N + i], s2);
    atomicAdd(&rows[3 * N + i], s3);
    atomicAdd(&rows[4 * N + i], se);

    // T partials: multiply by w_i, block-reduce, one atomic per scalar per block
    float t[9] = {t0e * wi, t1e * wi, t2e * wi, t3e * wi, tee * wi,
                  t00 * wi, t11 * wi, t22 * wi, t33 * wi};
    int lane = tid & 63, wave = tid >> 6;
#pragma unroll
    for (int k = 0; k < 9; ++k) t[k] = wave_reduce(t[k]);
    if (lane == 0) {
#pragma unroll
        for (int k = 0; k < 9; ++k) red[wave][k] = t[k];
    }
    __syncthreads();
    if (tid < 9)
        atomicAdd(&scal[tid], red[0][tid] + red[1][tid] + red[2][tid] + red[3][tid]);
}

// ---------------- kernel 3: final reduction + scalar math ----------------
__global__ __launch_bounds__(BLK) void k3_final(
        const float* __restrict__ rows, const float* __restrict__ scal,
        const float* __restrict__ wts, float* __restrict__ out, int N) {
    // accumulate SW[v] = sum_i w_i s_v(i)  (5)
    // and SWW pairs: [0..3]=s_c*s_e, [4]=s_e*s_e, [5..8]=s_c*s_c  (9)
    float acc[14];
#pragma unroll
    for (int k = 0; k < 14; ++k) acc[k] = 0.f;

    for (int i = threadIdx.x; i < N; i += BLK) {
        float w = wts[i];
        float s0 = rows[0 * N + i], s1 = rows[1 * N + i], s2 = rows[2 * N + i],
              s3 = rows[3 * N + i], sE = rows[4 * N + i];
        acc[0] += w * s0; acc[1] += w * s1; acc[2] += w * s2;
        acc[3] += w * s3; acc[4] += w * sE;
        float wE = w * sE;
        acc[5] += wE * s0; acc[6] += wE * s1; acc[7] += wE * s2; acc[8] += wE * s3;
        acc[9] += wE * sE;
        acc[10] += w * s0 * s0; acc[11] += w * s1 * s1;
        acc[12] += w * s2 * s2; acc[13] += w * s3 * s3;
    }

    __shared__ float red[4][14];
    int lane = threadIdx.x & 63, wave = threadIdx.x >> 6;
#pragma unroll
    for (int k = 0; k < 14; ++k) acc[k] = wave_reduce(acc[k]);
    if (lane == 0) {
#pragma unroll
        for (int k = 0; k < 14; ++k) red[wave][k] = acc[k];
    }
    __syncthreads();

    if (threadIdx.x == 0) {
        float SW[5], SWW_ce[4], SWW_ee, SWW_cc[4];
#pragma unroll
        for (int k = 0; k < 5; ++k) SW[k] = red[0][k] + red[1][k] + red[2][k] + red[3][k];
#pragma unroll
        for (int k = 0; k < 4; ++k) SWW_ce[k] = red[0][5 + k] + red[1][5 + k] + red[2][5 + k] + red[3][5 + k];
        SWW_ee = red[0][9] + red[1][9] + red[2][9] + red[3][9];
#pragma unroll
        for (int k = 0; k < 4; ++k) SWW_cc[k] = red[0][10 + k] + red[1][10 + k] + red[2][10 + k] + red[3][10 + k];

        float W = scal[10];
        float invW2 = 1.0f / (W * W);
        float invW3 = invW2 / W;

        // g_v = SW[v] / W^2
        float g0 = SW[0] * invW2, g1 = SW[1] * invW2, g2 = SW[2] * invW2,
              g3 = SW[3] * invW2, gE = SW[4] * invW2;

        // num_vw = T_raw/W^2 - 2*SWW/W^3 + g_v*g_w
        float num_ee = scal[4] * invW2 - 2.0f * SWW_ee * invW3 + gE * gE;
        float gc[4] = {g0, g1, g2, g3};
        float disco = 0.f;
#pragma unroll
        for (int c = 0; c < 4; ++c) {
            float num_ce = scal[c] * invW2 - 2.0f * SWW_ce[c] * invW3 + gc[c] * gE;
            float num_cc = scal[5 + c] * invW2 - 2.0f * SWW_cc[c] * invW3 + gc[c] * gc[c];
            disco += num_ce * rsqrtf(num_cc * num_ee);
        }
        disco *= 0.25f;

        float f = scal[9] / (float)N;
        out[0] = f;
        out[1] = disco;
        out[2] = f + LAM * disco;
    }
}

extern "C" void kernel_launch(void* const* d_in, const int* in_sizes, int n_in,
                              void* d_out, int out_size, void* d_ws, size_t ws_size,
                              hipStream_t stream) {
    const float* outs = (const float*)d_in[0];
    const int* labels = (const int*)d_in[1];
    const float* event = (const float*)d_in[2];
    const float* wts = (const float*)d_in[3];
    float* out = (float*)d_out;
    int N = in_sizes[1];  // 8192

    float* ws = (float*)d_ws;
    float* probs = ws;               // N*4
    float* rows = ws + (size_t)N * 4;  // 5*N
    float* scal = rows + (size_t)N * 5;  // 11 scalars

    // zero the accumulator region (rows + scalars); ws is poisoned each launch
    hipMemsetAsync(rows, 0, ((size_t)N * 5 + 11) * sizeof(float), stream);

    k1_rowprep<<<N / BLK, BLK, 0, stream>>>(outs, labels, wts, probs, scal);

    dim3 g2(N / BLK, JSPLIT);
    k2_pairs<<<g2, BLK, 0, stream>>>(probs, event, wts, rows, scal, N);

    k3_final<<<1, BLK, 0, stream>>>(rows, scal, wts, out, N);
}

// Round 2
// 113.152 us; speedup vs baseline: 1.1212x; 1.1212x over previous
//
#include <hip/hip_runtime.h>
#include <math.h>

#define BLK 256
#define IT 2
#define JSPLIT 32
#define LAM 0.1f

// ws layout (floats): probs[4N] | rows[5N] | scal[16] | kpart[32*12]
// scal[0..3] = T_ce raw (k2 atomics). kpart[b][0..11] = focal,W,M1[5],M2[5]

__device__ __forceinline__ float wave_reduce(float v) {
    v += __shfl_down(v, 32, 64);
    v += __shfl_down(v, 16, 64);
    v += __shfl_down(v, 8, 64);
    v += __shfl_down(v, 4, 64);
    v += __shfl_down(v, 2, 64);
    v += __shfl_down(v, 1, 64);
    return v;
}

// ---------------- kernel 1: softmax + focal + moments + zero accumulators ----
__global__ __launch_bounds__(BLK) void k1_rowprep(
        const float* __restrict__ outs, const int* __restrict__ labels,
        const float* __restrict__ event, const float* __restrict__ wts,
        float* __restrict__ probs, float* __restrict__ rows,
        float* __restrict__ scal, float* __restrict__ kpart, int N) {
    __shared__ float red[4][12];
    int i = blockIdx.x * BLK + threadIdx.x;
    float4 o = ((const float4*)outs)[i];
    float m = fmaxf(fmaxf(o.x, o.y), fmaxf(o.z, o.w));
    float e0 = expf(o.x - m), e1 = expf(o.y - m), e2 = expf(o.z - m), e3 = expf(o.w - m);
    float s = e0 + e1 + e2 + e3;
    float inv = 1.0f / s;
    float4 p = make_float4(e0 * inv, e1 * inv, e2 * inv, e3 * inv);
    ((float4*)probs)[i] = p;

    int l = labels[i];
    float ol = (l == 0) ? o.x : (l == 1) ? o.y : (l == 2) ? o.z : o.w;
    float logpt = ol - m - logf(s);
    float pt = expf(logpt);
    float w = wts[i];
    float ev = event[i];
    float om = 1.0f - pt;
    float focal = -om * om * logpt * w;

    // zero row-sum accumulators (k2 atomics land here; k1 completes first)
#pragma unroll
    for (int v = 0; v < 5; ++v) rows[v * N + i] = 0.f;
    if (blockIdx.x == 0 && threadIdx.x < 4) scal[threadIdx.x] = 0.f;

    // 12 block-partials: focal, W, M1[c0..c3,e], M2[c0..c3,e]
    float vals[12] = {focal, w,
                      w * p.x, w * p.y, w * p.z, w * p.w, w * ev,
                      w * p.x * p.x, w * p.y * p.y, w * p.z * p.z,
                      w * p.w * p.w, w * ev * ev};
    int lane = threadIdx.x & 63, wave = threadIdx.x >> 6;
#pragma unroll
    for (int k = 0; k < 12; ++k) {
        float r = wave_reduce(vals[k]);
        if (lane == 0) red[wave][k] = r;
    }
    __syncthreads();
    if (threadIdx.x < 12)
        kpart[blockIdx.x * 12 + threadIdx.x] =
            red[0][threadIdx.x] + red[1][threadIdx.x] + red[2][threadIdx.x] + red[3][threadIdx.x];
}

// ---------------- kernel 2: O(N^2) pair pass (row sums + 4 cross scalars) ----
__global__ __launch_bounds__(BLK) void k2_pairs(
        const float* __restrict__ probs, const float* __restrict__ event,
        const float* __restrict__ wts, float* __restrict__ rows,
        float* __restrict__ scal, int N) {
    __shared__ float4 jp[BLK];
    __shared__ float2 jew[BLK];
    __shared__ float red[4][4];

    int tid = threadIdx.x;
    int i0 = blockIdx.x * (BLK * IT) + tid;
    int i1 = i0 + BLK;
    float4 pA = ((const float4*)probs)[i0];
    float4 pB = ((const float4*)probs)[i1];
    float eA = event[i0], eB = event[i1];
    float wA = wts[i0], wB = wts[i1];

    int jcount = N / JSPLIT;
    int jbase = blockIdx.y * jcount;

    float sA0 = 0.f, sA1 = 0.f, sA2 = 0.f, sA3 = 0.f, sAe = 0.f;
    float sB0 = 0.f, sB1 = 0.f, sB2 = 0.f, sB3 = 0.f, sBe = 0.f;
    float tA0 = 0.f, tA1 = 0.f, tA2 = 0.f, tA3 = 0.f;
    float tB0 = 0.f, tB1 = 0.f, tB2 = 0.f, tB3 = 0.f;

    for (int jc = 0; jc < jcount; jc += BLK) {
        int j = jbase + jc + tid;
        jp[tid] = ((const float4*)probs)[j];
        jew[tid] = make_float2(event[j], wts[j]);
        __syncthreads();
#pragma unroll 4
        for (int jj = 0; jj < BLK; ++jj) {
            float4 p = jp[jj];
            float2 ew = jew[jj];
            float wj = ew.y;
            // i0
            {
                float d0 = fabsf(pA.x - p.x);
                float d1 = fabsf(pA.y - p.y);
                float d2 = fabsf(pA.z - p.z);
                float d3 = fabsf(pA.w - p.w);
                float de = fabsf(eA - ew.x);
                sA0 = fmaf(wj, d0, sA0);
                sA1 = fmaf(wj, d1, sA1);
                sA2 = fmaf(wj, d2, sA2);
                sA3 = fmaf(wj, d3, sA3);
                sAe = fmaf(wj, de, sAe);
                float wde = wj * de;
                tA0 = fmaf(wde, d0, tA0);
                tA1 = fmaf(wde, d1, tA1);
                tA2 = fmaf(wde, d2, tA2);
                tA3 = fmaf(wde, d3, tA3);
            }
            // i1
            {
                float d0 = fabsf(pB.x - p.x);
                float d1 = fabsf(pB.y - p.y);
                float d2 = fabsf(pB.z - p.z);
                float d3 = fabsf(pB.w - p.w);
                float de = fabsf(eB - ew.x);
                sB0 = fmaf(wj, d0, sB0);
                sB1 = fmaf(wj, d1, sB1);
                sB2 = fmaf(wj, d2, sB2);
                sB3 = fmaf(wj, d3, sB3);
                sBe = fmaf(wj, de, sBe);
                float wde = wj * de;
                tB0 = fmaf(wde, d0, tB0);
                tB1 = fmaf(wde, d1, tB1);
                tB2 = fmaf(wde, d2, tB2);
                tB3 = fmaf(wde, d3, tB3);
            }
        }
        __syncthreads();
    }

    // per-i raw row sums (accumulate across j-splits)
    atomicAdd(&rows[0 * N + i0], sA0);
    atomicAdd(&rows[1 * N + i0], sA1);
    atomicAdd(&rows[2 * N + i0], sA2);
    atomicAdd(&rows[3 * N + i0], sA3);
    atomicAdd(&rows[4 * N + i0], sAe);
    atomicAdd(&rows[0 * N + i1], sB0);
    atomicAdd(&rows[1 * N + i1], sB1);
    atomicAdd(&rows[2 * N + i1], sB2);
    atomicAdd(&rows[3 * N + i1], sB3);
    atomicAdd(&rows[4 * N + i1], sBe);

    // T_ce partials: scale by w_i, block-reduce, 4 atomics per block
    float t0 = tA0 * wA + tB0 * wB;
    float t1 = tA1 * wA + tB1 * wB;
    float t2 = tA2 * wA + tB2 * wB;
    float t3 = tA3 * wA + tB3 * wB;
    int lane = tid & 63, wave = tid >> 6;
    t0 = wave_reduce(t0); t1 = wave_reduce(t1);
    t2 = wave_reduce(t2); t3 = wave_reduce(t3);
    if (lane == 0) {
        red[wave][0] = t0; red[wave][1] = t1;
        red[wave][2] = t2; red[wave][3] = t3;
    }
    __syncthreads();
    if (tid < 4)
        atomicAdd(&scal[tid], red[0][tid] + red[1][tid] + red[2][tid] + red[3][tid]);
}

// ---------------- kernel 3: final reduction + scalar math ----------------
__global__ __launch_bounds__(1024) void k3_final(
        const float* __restrict__ rows, const float* __restrict__ scal,
        const float* __restrict__ wts, const float* __restrict__ kpart,
        float* __restrict__ out, int N) {
    __shared__ float red[16][14];
    __shared__ float fin[12];
    int tid = threadIdx.x, lane = tid & 63, wave = tid >> 6;

    // reduce the 32 k1 block-partials (wave 0 only)
    if (wave == 0) {
#pragma unroll
        for (int k = 0; k < 12; ++k) {
            float v = (lane < 32) ? kpart[lane * 12 + k] : 0.f;
            v = wave_reduce(v);
            if (lane == 0) fin[k] = v;
        }
    }

    float acc[14];
#pragma unroll
    for (int k = 0; k < 14; ++k) acc[k] = 0.f;

    for (int i = tid; i < N; i += 1024) {
        float w = wts[i];
        float s0 = rows[0 * N + i], s1 = rows[1 * N + i], s2 = rows[2 * N + i],
              s3 = rows[3 * N + i], sE = rows[4 * N + i];
        acc[0] += w * s0; acc[1] += w * s1; acc[2] += w * s2;
        acc[3] += w * s3; acc[4] += w * sE;
        float wE = w * sE;
        acc[5] += wE * s0; acc[6] += wE * s1; acc[7] += wE * s2; acc[8] += wE * s3;
        acc[9] += wE * sE;
        acc[10] += w * s0 * s0; acc[11] += w * s1 * s1;
        acc[12] += w * s2 * s2; acc[13] += w * s3 * s3;
    }

#pragma unroll
    for (int k = 0; k < 14; ++k) acc[k] = wave_reduce(acc[k]);
    if (lane == 0) {
#pragma unroll
        for (int k = 0; k < 14; ++k) red[wave][k] = acc[k];
    }
    __syncthreads();

    if (tid == 0) {
        float SW[5], SWW_ce[4], SWW_ee, SWW_cc[4];
#pragma unroll
        for (int k = 0; k < 5; ++k) {
            float a = 0.f;
            for (int wv = 0; wv < 16; ++wv) a += red[wv][k];
            SW[k] = a;
        }
#pragma unroll
        for (int k = 0; k < 4; ++k) {
            float a = 0.f;
            for (int wv = 0; wv < 16; ++wv) a += red[wv][5 + k];
            SWW_ce[k] = a;
        }
        {
            float a = 0.f;
            for (int wv = 0; wv < 16; ++wv) a += red[wv][9];
            SWW_ee = a;
        }
#pragma unroll
        for (int k = 0; k < 4; ++k) {
            float a = 0.f;
            for (int wv = 0; wv < 16; ++wv) a += red[wv][10 + k];
            SWW_cc[k] = a;
        }

        float focal_sum = fin[0];
        float W = fin[1];
        float M1[5] = {fin[2], fin[3], fin[4], fin[5], fin[6]};
        float M2[5] = {fin[7], fin[8], fin[9], fin[10], fin[11]};

        float invW2 = 1.0f / (W * W);
        float invW3 = invW2 / W;

        float g[5];
#pragma unroll
        for (int v = 0; v < 5; ++v) g[v] = SW[v] * invW2;
        float gE = g[4];

        // closed-form same-channel raw T: 2*(W*M2 - M1^2)
        float Tee = 2.0f * (W * M2[4] - M1[4] * M1[4]);
        float num_ee = Tee * invW2 - 2.0f * SWW_ee * invW3 + gE * gE;

        float disco = 0.f;
#pragma unroll
        for (int c = 0; c < 4; ++c) {
            float Tcc = 2.0f * (W * M2[c] - M1[c] * M1[c]);
            float num_cc = Tcc * invW2 - 2.0f * SWW_cc[c] * invW3 + g[c] * g[c];
            float num_ce = scal[c] * invW2 - 2.0f * SWW_ce[c] * invW3 + g[c] * gE;
            disco += num_ce * rsqrtf(num_cc * num_ee);
        }
        disco *= 0.25f;

        float f = focal_sum / (float)N;
        out[0] = f;
        out[1] = disco;
        out[2] = f + LAM * disco;
    }
}

extern "C" void kernel_launch(void* const* d_in, const int* in_sizes, int n_in,
                              void* d_out, int out_size, void* d_ws, size_t ws_size,
                              hipStream_t stream) {
    const float* outs = (const float*)d_in[0];
    const int* labels = (const int*)d_in[1];
    const float* event = (const float*)d_in[2];
    const float* wts = (const float*)d_in[3];
    float* out = (float*)d_out;
    int N = in_sizes[1];  // 8192

    float* ws = (float*)d_ws;
    float* probs = ws;                    // 4N
    float* rows = probs + (size_t)N * 4;  // 5N
    float* scal = rows + (size_t)N * 5;   // 16
    float* kpart = scal + 16;             // 32*12

    k1_rowprep<<<N / BLK, BLK, 0, stream>>>(outs, labels, event, wts, probs, rows, scal, kpart, N);

    dim3 g2(N / (BLK * IT), JSPLIT);
    k2_pairs<<<g2, BLK, 0, stream>>>(probs, event, wts, rows, scal, N);

    k3_final<<<1, 1024, 0, stream>>>(rows, scal, wts, kpart, out, N);
}